// Round 6
// baseline (538.708 us; speedup 1.0000x reference)
//
#include <hip/hip_runtime.h>

// SkipConnection MLP, fp32 VALU (only numerically-viable pipe: fp32 reassoc
// already costs 0.23% of the 2% budget; amplification ~2e4*eps kills
// bf16/fp16/MFMA paths outright).
//
// Layer body is at its 24-op floor (16 fma + 4 bias-add + 4 max):
//  - residual: o = max(Sum o_j*W + (b+s), s)   [relu(p)+s == max(p+s,s), s>=0]
//  - plain:    o = max(Sum o_j*W + b, 0)
// This round: unroll-by-15 instead of full unroll (24 KB straight-line body
// was at the 32 KB I$ edge; occupancy dropped 91->79). Base steps by 15 so
// base%5==0 and flags fold to the compile-time j%5 in every copy.

#define NLAYERS 99

template <bool RESIDUAL>
__device__ __forceinline__ void layer_step(
    const float* __restrict__ W, const float* __restrict__ b,
    float& o0, float& o1, float& o2, float& o3,
    float& s0, float& s1, float& s2, float& s3)
{
    if (RESIDUAL) {
        float p0 = fmaf(o0, W[ 0], fmaf(o1, W[ 4], fmaf(o2, W[ 8], fmaf(o3, W[12], b[0] + s0))));
        float p1 = fmaf(o0, W[ 1], fmaf(o1, W[ 5], fmaf(o2, W[ 9], fmaf(o3, W[13], b[1] + s1))));
        float p2 = fmaf(o0, W[ 2], fmaf(o1, W[ 6], fmaf(o2, W[10], fmaf(o3, W[14], b[2] + s2))));
        float p3 = fmaf(o0, W[ 3], fmaf(o1, W[ 7], fmaf(o2, W[11], fmaf(o3, W[15], b[3] + s3))));
        o0 = fmaxf(p0, s0);
        o1 = fmaxf(p1, s1);
        o2 = fmaxf(p2, s2);
        o3 = fmaxf(p3, s3);
        s0 = o0; s1 = o1; s2 = o2; s3 = o3;
    } else {
        float p0 = fmaf(o0, W[ 0], fmaf(o1, W[ 4], fmaf(o2, W[ 8], o3 * W[12]))) + b[0];
        float p1 = fmaf(o0, W[ 1], fmaf(o1, W[ 5], fmaf(o2, W[ 9], o3 * W[13]))) + b[1];
        float p2 = fmaf(o0, W[ 2], fmaf(o1, W[ 6], fmaf(o2, W[10], o3 * W[14]))) + b[2];
        float p3 = fmaf(o0, W[ 3], fmaf(o1, W[ 7], fmaf(o2, W[11], o3 * W[15]))) + b[3];
        o0 = fmaxf(p0, 0.f);
        o1 = fmaxf(p1, 0.f);
        o2 = fmaxf(p2, 0.f);
        o3 = fmaxf(p3, 0.f);
    }
}

__global__ __launch_bounds__(256) void skipmlp_kernel(
    const float* __restrict__ x,      // [B,2]
    const float* __restrict__ W_in,   // [2,4]
    const float* __restrict__ b_in,   // [4]
    const float* __restrict__ Ws,     // [99,4,4]
    const float* __restrict__ bs,     // [99,4]
    const float* __restrict__ W_out,  // [4,1]
    const float* __restrict__ b_out,  // [1]
    float* __restrict__ out,          // [B,1]
    int B)
{
    int row = blockIdx.x * blockDim.x + threadIdx.x;
    if (row >= B) return;

    const float2 xv = *reinterpret_cast<const float2*>(x + (size_t)row * 2u);

    float o0 = fmaxf(fmaf(xv.x, W_in[0], fmaf(xv.y, W_in[4], b_in[0])), 0.f);
    float o1 = fmaxf(fmaf(xv.x, W_in[1], fmaf(xv.y, W_in[5], b_in[1])), 0.f);
    float o2 = fmaxf(fmaf(xv.x, W_in[2], fmaf(xv.y, W_in[6], b_in[2])), 0.f);
    float o3 = fmaxf(fmaf(xv.x, W_in[3], fmaf(xv.y, W_in[7], b_in[3])), 0.f);

    float s0 = o0, s1 = o1, s2 = o2, s3 = o3;

    // 90 layers in 6 blocks of 15; base%15==0 => base%5==0 => flag is j%5.
    for (int base = 0; base < 90; base += 15) {
        const float* __restrict__ Wg = Ws + base * 16;
        const float* __restrict__ bg = bs + base * 4;
        #pragma unroll
        for (int j = 0; j < 15; ++j) {
            if ((j % 5) != 0)
                layer_step<true >(Wg + j * 16, bg + j * 4, o0, o1, o2, o3, s0, s1, s2, s3);
            else
                layer_step<false>(Wg + j * 16, bg + j * 4, o0, o1, o2, o3, s0, s1, s2, s3);
        }
    }
    // tail: layers 90..98 (90%5==0 => flag is j%5 again)
    {
        const float* __restrict__ Wg = Ws + 90 * 16;
        const float* __restrict__ bg = bs + 90 * 4;
        #pragma unroll
        for (int j = 0; j < 9; ++j) {
            if ((j % 5) != 0)
                layer_step<true >(Wg + j * 16, bg + j * 4, o0, o1, o2, o3, s0, s1, s2, s3);
            else
                layer_step<false>(Wg + j * 16, bg + j * 4, o0, o1, o2, o3, s0, s1, s2, s3);
        }
    }

    float y = fmaf(o0, W_out[0], fmaf(o1, W_out[1], fmaf(o2, W_out[2], o3 * W_out[3]))) + b_out[0];
    out[row] = y;
}

extern "C" void kernel_launch(void* const* d_in, const int* in_sizes, int n_in,
                              void* d_out, int out_size, void* d_ws, size_t ws_size,
                              hipStream_t stream) {
    const float* x     = (const float*)d_in[0];
    const float* W_in  = (const float*)d_in[1];
    const float* b_in  = (const float*)d_in[2];
    const float* Ws    = (const float*)d_in[3];
    const float* bs    = (const float*)d_in[4];
    const float* W_out = (const float*)d_in[5];
    const float* b_out = (const float*)d_in[6];
    float* out = (float*)d_out;

    const int B = in_sizes[0] / 2;  // x is [B,2]
    const int block = 256;
    const int grid = (B + block - 1) / block;

    skipmlp_kernel<<<grid, block, 0, stream>>>(x, W_in, b_in, Ws, bs, W_out, b_out, out, B);
}